// Round 16
// baseline (116.078 us; speedup 1.0000x reference)
//
#include <hip/hip_runtime.h>
#include <hip/hip_bf16.h>

#define B_ 4
#define H_ 4
#define N_ 4096
#define D_ 64
#define E_ 256
#define KVB 64
#define QBLK 128            // 4 waves: 2 q-groups(64q) x 2 kv-halves, wave-private staging
#define NT (N_ / KVB)

typedef short short8 __attribute__((ext_vector_type(8)));
typedef float f32x4 __attribute__((ext_vector_type(4)));
typedef float f32x16 __attribute__((ext_vector_type(16)));

__device__ __forceinline__ ushort f2bf(float f) {
  union { float f; unsigned u; } a; a.f = f;
  unsigned r = a.u + 0x7fffu + ((a.u >> 16) & 1u);
  return (ushort)(r >> 16);
}

__device__ __forceinline__ uint4 pack8(float a0, float a1, float a2, float a3,
                                       float a4, float a5, float a6, float a7) {
  uint4 u;
  u.x = (unsigned)f2bf(a0) | ((unsigned)f2bf(a1) << 16);
  u.y = (unsigned)f2bf(a2) | ((unsigned)f2bf(a3) << 16);
  u.z = (unsigned)f2bf(a4) | ((unsigned)f2bf(a5) << 16);
  u.w = (unsigned)f2bf(a6) | ((unsigned)f2bf(a7) << 16);
  return u;
}

__device__ __forceinline__ unsigned cvt_pk_bf16(float lo, float hi) {
  unsigned r;
  asm("v_cvt_pk_bf16_f32 %0, %1, %2" : "=v"(r) : "v"(lo), "v"(hi));
  return r;
}

__device__ __forceinline__ void permlane32_swap(unsigned &a, unsigned &b) {
  asm volatile("v_permlane32_swap_b32 %0, %1" : "+v"(a), "+v"(b));
}

// async global->LDS: per-lane global src, wave-uniform LDS base (+lane*16 implicit)
__device__ __forceinline__ void gload16(const void* g, void* l) {
  __builtin_amdgcn_global_load_lds(
      (const __attribute__((address_space(1))) void*)g,
      (__attribute__((address_space(3))) void*)l, 16, 0, 0);
}

// ---------------- W cast: f32 -> bf16 ----------------
__global__ void cast_w_kernel(const float* __restrict__ W, ushort* __restrict__ Wb) {
  int i = blockIdx.x * blockDim.x + threadIdx.x;
  float4 x = ((const float4*)W)[i];
  ushort4 o;
  o.x = f2bf(x.x); o.y = f2bf(x.y); o.z = f2bf(x.z); o.w = f2bf(x.w);
  ((ushort4*)Wb)[i] = o;
}

// ---------------- Pre-pass: emit K and V^T tiles in MFMA-FRAGMENT order ----------------
__global__ void prep_kv(const float* __restrict__ k, const float* __restrict__ v,
                        ushort* __restrict__ Kb, ushort* __restrict__ Vtb) {
  __shared__ float kt[64][65];
  __shared__ float vt[64][65];
  const int gid = blockIdx.x;            // bh*NT + t
  const int bh = gid >> 6, t = gid & 63;
  const int b = bh >> 2, h = bh & 3;
  const int tid = threadIdx.x;
  const int rr = tid >> 4, cc = (tid & 15) * 4;
  const float* kg = k + ((size_t)b * N_ + t * 64) * E_ + h * 64;
  const float* vg = v + ((size_t)b * N_ + t * 64) * E_ + h * 64;
  ushort* ko = Kb + (size_t)gid * 4096;
  ushort* vo = Vtb + (size_t)gid * 4096;

  for (int it = 0; it < 4; ++it) {
    int r = rr + it * 16;
    float4 kx = *(const float4*)(kg + (size_t)r * E_ + cc);
    float4 vx = *(const float4*)(vg + (size_t)r * E_ + cc);
    kt[r][cc] = kx.x; kt[r][cc + 1] = kx.y; kt[r][cc + 2] = kx.z; kt[r][cc + 3] = kx.w;
    vt[r][cc] = vx.x; vt[r][cc + 1] = vx.y; vt[r][cc + 2] = vx.z; vt[r][cc + 3] = vx.w;
  }
  __syncthreads();

  for (int j = 0; j < 2; ++j) {
    int u = j * 256 + tid;
    int frag = u >> 6, l = u & 63;
    int a = (frag >> 2) * 32 + (l & 31);
    int c0 = (frag & 3) * 16 + ((l >> 5) & 1) * 8;
    *(uint4*)(ko + u * 8) = pack8(kt[a][c0], kt[a][c0 + 1], kt[a][c0 + 2], kt[a][c0 + 3],
                                  kt[a][c0 + 4], kt[a][c0 + 5], kt[a][c0 + 6], kt[a][c0 + 7]);
    *(uint4*)(vo + u * 8) = pack8(vt[c0][a], vt[c0 + 1][a], vt[c0 + 2][a], vt[c0 + 3][a],
                                  vt[c0 + 4][a], vt[c0 + 5][a], vt[c0 + 6][a], vt[c0 + 7][a]);
  }
}

// ---------------- Flash attention: wave-private double-buffer, NO in-loop barriers ----------------
__launch_bounds__(256, 2)
__global__ void attn_kernel(const float* __restrict__ q,
                            const ushort* __restrict__ Kb,
                            const ushort* __restrict__ Vtb,
                            ushort* __restrict__ X) {
  // SM[wave][dbuf][K=0/V=1][2048 ushort] = 64 KB. Each wave owns SM[wid] exclusively
  // during the loop; epilogue (after __syncthreads) reuses first 32 KB as f32 Ox.
  __shared__ __attribute__((aligned(16))) ushort SM[4][2][2][2048];
  __shared__ float Lb[2][2][32];
  __shared__ float Lb2[2][2][32];

  const int bid = blockIdx.x;
  const int swz = (bid & 7) * 64 + (bid >> 3);   // 512 blocks, bijective, XCD-contiguous
  const int bh = swz >> 5;
  const int qt = swz & 31;
  const int b = bh >> 2, h = bh & 3;
  const int tid = threadIdx.x;
  const int wid = tid >> 6;
  const int wq = wid & 1;        // q-block of 64 rows
  const int kh = wid >> 1;       // kv-half of each 64-kv tile
  const int lane = tid & 63;
  const int ln = lane & 31;
  const int hi = lane >> 5;

  // Global frag-ordered tiles. This wave's K-slice = frags [kh*4 .. kh*4+3] (contiguous 4KB);
  // V^T-slice = frags {kh*2, kh*2+1} and {4+kh*2, 4+kh*2+1} (two contiguous 2KB pieces).
  const char* Kg = (const char*)Kb + (size_t)bh * NT * 8192 + kh * 4096 + lane * 16;
  const char* Vg = (const char*)Vtb + (size_t)bh * NT * 8192 + kh * 2048 + lane * 16;

  char* Kl0 = (char*)&SM[wid][0][0][0];
  char* Vl0 = (char*)&SM[wid][0][1][0];
  char* Kl1 = (char*)&SM[wid][1][0][0];
  char* Vl1 = (char*)&SM[wid][1][1][0];

  // ---- Q B-fragments for both q-groups, scale*log2e folded ----
  const float SC = 0.125f * 1.44269504f;
  const int qrow0 = qt * QBLK + wq * 64;
  short8 qf[2][4];
#pragma unroll
  for (int qg = 0; qg < 2; ++qg) {
    const float* Qg = q + ((size_t)b * N_ + qrow0 + qg * 32 + ln) * E_ + h * D_;
#pragma unroll
    for (int ks = 0; ks < 4; ++ks) {
      const float* p = Qg + ks * 16 + hi * 8;
      float4 x0 = *(const float4*)(p);
      float4 x1 = *(const float4*)(p + 4);
      short8 f;
      f[0] = (short)f2bf(x0.x * SC); f[1] = (short)f2bf(x0.y * SC);
      f[2] = (short)f2bf(x0.z * SC); f[3] = (short)f2bf(x0.w * SC);
      f[4] = (short)f2bf(x1.x * SC); f[5] = (short)f2bf(x1.y * SC);
      f[6] = (short)f2bf(x1.z * SC); f[7] = (short)f2bf(x1.w * SC);
      qf[qg][ks] = f;
    }
  }

  f32x16 O00 = (f32x16)0.0f, O01 = (f32x16)0.0f;   // [qg0][db0/1]
  f32x16 O10 = (f32x16)0.0f, O11 = (f32x16)0.0f;   // [qg1][db0/1]
  float lsum0 = 0.f, lsum1 = 0.f;

  // stage this wave's 8KB slice of tile t into buffer (Kl,Vl): 8 async 1KB chunks
  auto STAGE = [&](char* Kl, char* Vl, int t) {
    const char* kg = Kg + (size_t)t * 8192;
    const char* vg = Vg + (size_t)t * 8192;
#pragma unroll
    for (int c = 0; c < 4; ++c)
      gload16(kg + c * 1024, Kl + c * 1024);
    gload16(vg,               Vl);
    gload16(vg + 1024,        Vl + 1024);
    gload16(vg + 4096,        Vl + 2048);
    gload16(vg + 4096 + 1024, Vl + 3072);
  };

  // ---- prologue: stage tile 0, full drain (also drains Q loads -> clean ledger) ----
  STAGE(Kl0, Vl0, 0);
  asm volatile("s_waitcnt vmcnt(0)" ::: "memory");
  __builtin_amdgcn_sched_barrier(0);

  for (int t = 0; t < NT; ++t) {
    const int curb = t & 1;
    char* Klc = curb ? Kl1 : Kl0;
    char* Vlc = curb ? Vl1 : Vl0;

    // ---- issue next tile into the other private buffer; wait ONLY tile t's 8 ----
    if (t + 1 < NT) {
      STAGE(curb ? Kl0 : Kl1, curb ? Vl0 : Vl1, t + 1);
      __builtin_amdgcn_sched_barrier(0);
      asm volatile("s_waitcnt vmcnt(8)" ::: "memory");   // retire tile t's loads; t+1 stays in flight
    } else {
      asm volatile("s_waitcnt vmcnt(0)" ::: "memory");
    }
    __builtin_amdgcn_sched_barrier(0);

    // ---- K A-fragments (wave-private, lane-linear, conflict-free) ----
    short8 kf[4];
#pragma unroll
    for (int ks = 0; ks < 4; ++ks)
      kf[ks] = *(short8*)(Klc + ks * 1024 + lane * 16);

    // ---- S^T = K Q^T for both q-groups ----
    f32x16 S0 = (f32x16)0.0f, S1 = (f32x16)0.0f;
    __builtin_amdgcn_s_setprio(1);
#pragma unroll
    for (int ks = 0; ks < 4; ++ks) {
      S0 = __builtin_amdgcn_mfma_f32_32x32x16_bf16(kf[ks], qf[0][ks], S0, 0, 0, 0);
      S1 = __builtin_amdgcn_mfma_f32_32x32x16_bf16(kf[ks], qf[1][ks], S1, 0, 0, 0);
    }
    __builtin_amdgcn_s_setprio(0);

    // ---- V B-fragments: local chunk (db*2+s) ----
    short8 vf[2][2];
#pragma unroll
    for (int db = 0; db < 2; ++db)
#pragma unroll
      for (int s = 0; s < 2; ++s)
        vf[db][s] = *(short8*)(Vlc + (db * 2 + s) * 1024 + lane * 16);

    // ---- P = 2^S; tree sums ----
    float p0[16], p1[16];
#pragma unroll
    for (int i = 0; i < 16; ++i) {
      p0[i] = __builtin_amdgcn_exp2f(S0[i]);
      p1[i] = __builtin_amdgcn_exp2f(S1[i]);
    }
    {
      float s1[8];
#pragma unroll
      for (int i = 0; i < 8; ++i) s1[i] = p0[2 * i] + p0[2 * i + 1];
#pragma unroll
      for (int i = 0; i < 4; ++i) s1[i] = s1[2 * i] + s1[2 * i + 1];
      lsum0 += (s1[0] + s1[1]) + (s1[2] + s1[3]);
#pragma unroll
      for (int i = 0; i < 8; ++i) s1[i] = p1[2 * i] + p1[2 * i + 1];
#pragma unroll
      for (int i = 0; i < 4; ++i) s1[i] = s1[2 * i] + s1[2 * i + 1];
      lsum1 += (s1[0] + s1[1]) + (s1[2] + s1[3]);
    }

    // ---- pack P -> PV A-frags (cvt_pk + permlane32_swap) ----
    short8 pa0[2], pa1[2];
#pragma unroll
    for (int s = 0; s < 2; ++s) {
      int base = s * 8;
      {
        unsigned w0 = cvt_pk_bf16(p0[base + 0], p0[base + 1]);
        unsigned w2 = cvt_pk_bf16(p0[base + 4], p0[base + 5]);
        permlane32_swap(w0, w2);
        unsigned w1 = cvt_pk_bf16(p0[base + 2], p0[base + 3]);
        unsigned w3 = cvt_pk_bf16(p0[base + 6], p0[base + 7]);
        permlane32_swap(w1, w3);
        uint4 u; u.x = w0; u.y = w1; u.z = w2; u.w = w3;
        union { uint4 u4; short8 s8; } cv; cv.u4 = u;
        pa0[s] = cv.s8;
      }
      {
        unsigned w0 = cvt_pk_bf16(p1[base + 0], p1[base + 1]);
        unsigned w2 = cvt_pk_bf16(p1[base + 4], p1[base + 5]);
        permlane32_swap(w0, w2);
        unsigned w1 = cvt_pk_bf16(p1[base + 2], p1[base + 3]);
        unsigned w3 = cvt_pk_bf16(p1[base + 6], p1[base + 7]);
        permlane32_swap(w1, w3);
        uint4 u; u.x = w0; u.y = w1; u.z = w2; u.w = w3;
        union { uint4 u4; short8 s8; } cv; cv.u4 = u;
        pa1[s] = cv.s8;
      }
    }

    // ---- O += P V (both q-groups share vf) ----
    __builtin_amdgcn_s_setprio(1);
#pragma unroll
    for (int s = 0; s < 2; ++s) {
      O00 = __builtin_amdgcn_mfma_f32_32x32x16_bf16(pa0[s], vf[0][s], O00, 0, 0, 0);
      O01 = __builtin_amdgcn_mfma_f32_32x32x16_bf16(pa0[s], vf[1][s], O01, 0, 0, 0);
      O10 = __builtin_amdgcn_mfma_f32_32x32x16_bf16(pa1[s], vf[0][s], O10, 0, 0, 0);
      O11 = __builtin_amdgcn_mfma_f32_32x32x16_bf16(pa1[s], vf[1][s], O11, 0, 0, 0);
    }
    __builtin_amdgcn_s_setprio(0);

    // fence the round: next round's STAGE must not float up into this round
    __builtin_amdgcn_sched_barrier(0);
  }

  // ---- epilogue: all waves done (Ox aliases waves 0/1's staging buffers) ----
  __syncthreads();

  float l0 = lsum0 + __shfl_xor(lsum0, 32);
  float l1 = lsum1 + __shfl_xor(lsum1, 32);
  float* Ox = (float*)&SM[0][0][0][0];   // first 32 KB
  if (kh) {
    if (lane < 32) { Lb[wq][0][ln] = l0; Lb[wq][1][ln] = l1; }
#pragma unroll
    for (int r2 = 0; r2 < 16; ++r2) {
      Ox[wq * 4096 + 0 * 2048 + 0 * 1024 + r2 * 64 + lane] = O00[r2];
      Ox[wq * 4096 + 0 * 2048 + 1 * 1024 + r2 * 64 + lane] = O01[r2];
      Ox[wq * 4096 + 1 * 2048 + 0 * 1024 + r2 * 64 + lane] = O10[r2];
      Ox[wq * 4096 + 1 * 2048 + 1 * 1024 + r2 * 64 + lane] = O11[r2];
    }
  }
  __syncthreads();
  if (!kh) {
    float lt0 = l0 + Lb[wq][0][ln];
    float lt1 = l1 + Lb[wq][1][ln];
    if (lane < 32) { Lb2[wq][0][ln] = lt0; Lb2[wq][1][ln] = lt1; }
    asm volatile("" ::: "memory");
#pragma unroll
    for (int r2 = 0; r2 < 16; ++r2) {
      O00[r2] += Ox[wq * 4096 + 0 * 2048 + 0 * 1024 + r2 * 64 + lane];
      O01[r2] += Ox[wq * 4096 + 0 * 2048 + 1 * 1024 + r2 * 64 + lane];
      O10[r2] += Ox[wq * 4096 + 1 * 2048 + 0 * 1024 + r2 * 64 + lane];
      O11[r2] += Ox[wq * 4096 + 1 * 2048 + 1 * 1024 + r2 * 64 + lane];
    }
    ushort* Xp = X + ((size_t)b * N_) * E_ + h * D_;
#pragma unroll
    for (int r2 = 0; r2 < 16; ++r2) {
      int crow = (r2 & 3) + 8 * (r2 >> 2) + 4 * hi;
      float i0 = 1.0f / Lb2[wq][0][crow];
      float i1 = 1.0f / Lb2[wq][1][crow];
      int q0 = qrow0 + crow;
      int q1 = qrow0 + 32 + crow;
      Xp[(size_t)q0 * E_ + ln]      = f2bf(O00[r2] * i0);
      Xp[(size_t)q0 * E_ + 32 + ln] = f2bf(O01[r2] * i0);
      Xp[(size_t)q1 * E_ + ln]      = f2bf(O10[r2] * i1);
      Xp[(size_t)q1 * E_ + 32 + ln] = f2bf(O11[r2] * i1);
    }
  }
}

// ---------------- Output projection: out = X @ W^T + b ----------------
__launch_bounds__(256, 2)
__global__ void proj_kernel(const ushort* __restrict__ X, const ushort* __restrict__ Wb,
                            const float* __restrict__ bias, float* __restrict__ out) {
  const int m0   = blockIdx.x * 64;
  const int tid  = threadIdx.x;
  const int wid  = tid >> 6;
  const int lane = tid & 63;
  const int g    = lane >> 4;
  const int lr   = lane & 15;
  const int n0   = wid * 64;

  f32x4 acc[4][4];
  for (int mb = 0; mb < 4; ++mb)
    for (int nb = 0; nb < 4; ++nb)
      acc[mb][nb] = (f32x4){0.f, 0.f, 0.f, 0.f};

  for (int k0 = 0; k0 < E_; k0 += 32) {
    short8 af[4], bfr[4];
    for (int mb = 0; mb < 4; ++mb)
      af[mb] = *(const short8*)(X + (size_t)(m0 + mb * 16 + lr) * E_ + k0 + g * 8);
    for (int nb = 0; nb < 4; ++nb)
      bfr[nb] = *(const short8*)(Wb + (size_t)(n0 + nb * 16 + lr) * E_ + k0 + g * 8);
    for (int mb = 0; mb < 4; ++mb)
      for (int nb = 0; nb < 4; ++nb)
        acc[mb][nb] = __builtin_amdgcn_mfma_f32_16x16x32_bf16(af[mb], bfr[nb], acc[mb][nb], 0, 0, 0);
  }

  for (int nb = 0; nb < 4; ++nb) {
    float bv = bias[n0 + nb * 16 + lr];
    for (int mb = 0; mb < 4; ++mb)
      for (int r = 0; r < 4; ++r)
        out[(size_t)(m0 + mb * 16 + g * 4 + r) * E_ + n0 + nb * 16 + lr] = acc[mb][nb][r] + bv;
  }
}

extern "C" void kernel_launch(void* const* d_in, const int* in_sizes, int n_in,
                              void* d_out, int out_size, void* d_ws, size_t ws_size,
                              hipStream_t stream) {
  const float* q    = (const float*)d_in[0];
  const float* k    = (const float*)d_in[1];
  const float* v    = (const float*)d_in[2];
  const float* W    = (const float*)d_in[3];
  const float* bias = (const float*)d_in[4];

  char* ws = (char*)d_ws;
  ushort* X   = (ushort*)ws;                                  // 8 MiB
  ushort* Wb  = (ushort*)(ws + 8388608);                      // 128 KiB
  ushort* Kb  = (ushort*)(ws + 8388608 + 131072);             // 8 MiB
  ushort* Vtb = (ushort*)(ws + 8388608 + 131072 + 8388608);   // 8 MiB

  cast_w_kernel<<<64, 256, 0, stream>>>(W, Wb);
  prep_kv<<<B_ * H_ * NT, 256, 0, stream>>>(k, v, Kb, Vtb);
  attn_kernel<<<B_ * H_ * (N_ / QBLK), 256, 0, stream>>>(q, Kb, Vtb, X);
  proj_kernel<<<(B_ * N_) / 64, 256, 0, stream>>>(X, Wb, bias, (float*)d_out);
}

// Round 17
// 109.774 us; speedup vs baseline: 1.0574x; 1.0574x over previous
//
#include <hip/hip_runtime.h>
#include <hip/hip_bf16.h>

#define B_ 4
#define H_ 4
#define N_ 4096
#define D_ 64
#define E_ 256
#define KVB 64
#define QBLK 128            // 4 waves: 2 q-groups(64q) x 2 kv-halves
#define NT (N_ / KVB)

typedef short short8 __attribute__((ext_vector_type(8)));
typedef float f32x4 __attribute__((ext_vector_type(4)));
typedef float f32x16 __attribute__((ext_vector_type(16)));

__device__ __forceinline__ ushort f2bf(float f) {
  union { float f; unsigned u; } a; a.f = f;
  unsigned r = a.u + 0x7fffu + ((a.u >> 16) & 1u);
  return (ushort)(r >> 16);
}

__device__ __forceinline__ uint4 pack8(float a0, float a1, float a2, float a3,
                                       float a4, float a5, float a6, float a7) {
  uint4 u;
  u.x = (unsigned)f2bf(a0) | ((unsigned)f2bf(a1) << 16);
  u.y = (unsigned)f2bf(a2) | ((unsigned)f2bf(a3) << 16);
  u.z = (unsigned)f2bf(a4) | ((unsigned)f2bf(a5) << 16);
  u.w = (unsigned)f2bf(a6) | ((unsigned)f2bf(a7) << 16);
  return u;
}

__device__ __forceinline__ unsigned cvt_pk_bf16(float lo, float hi) {
  unsigned r;
  asm("v_cvt_pk_bf16_f32 %0, %1, %2" : "=v"(r) : "v"(lo), "v"(hi));
  return r;
}

__device__ __forceinline__ void permlane32_swap(unsigned &a, unsigned &b) {
  asm volatile("v_permlane32_swap_b32 %0, %1" : "+v"(a), "+v"(b));
}

// ---------------- W cast: f32 -> bf16 ----------------
__global__ void cast_w_kernel(const float* __restrict__ W, ushort* __restrict__ Wb) {
  int i = blockIdx.x * blockDim.x + threadIdx.x;
  float4 x = ((const float4*)W)[i];
  ushort4 o;
  o.x = f2bf(x.x); o.y = f2bf(x.y); o.z = f2bf(x.z); o.w = f2bf(x.w);
  ((ushort4*)Wb)[i] = o;
}

// ---------------- Pre-pass: emit K and V^T tiles in MFMA-FRAGMENT order ----------------
__global__ void prep_kv(const float* __restrict__ k, const float* __restrict__ v,
                        ushort* __restrict__ Kb, ushort* __restrict__ Vtb) {
  __shared__ float kt[64][65];
  __shared__ float vt[64][65];
  const int gid = blockIdx.x;            // bh*NT + t
  const int bh = gid >> 6, t = gid & 63;
  const int b = bh >> 2, h = bh & 3;
  const int tid = threadIdx.x;
  const int rr = tid >> 4, cc = (tid & 15) * 4;
  const float* kg = k + ((size_t)b * N_ + t * 64) * E_ + h * 64;
  const float* vg = v + ((size_t)b * N_ + t * 64) * E_ + h * 64;
  ushort* ko = Kb + (size_t)gid * 4096;
  ushort* vo = Vtb + (size_t)gid * 4096;

  for (int it = 0; it < 4; ++it) {
    int r = rr + it * 16;
    float4 kx = *(const float4*)(kg + (size_t)r * E_ + cc);
    float4 vx = *(const float4*)(vg + (size_t)r * E_ + cc);
    kt[r][cc] = kx.x; kt[r][cc + 1] = kx.y; kt[r][cc + 2] = kx.z; kt[r][cc + 3] = kx.w;
    vt[r][cc] = vx.x; vt[r][cc + 1] = vx.y; vt[r][cc + 2] = vx.z; vt[r][cc + 3] = vx.w;
  }
  __syncthreads();

  for (int j = 0; j < 2; ++j) {
    int u = j * 256 + tid;
    int frag = u >> 6, l = u & 63;
    int a = (frag >> 2) * 32 + (l & 31);
    int c0 = (frag & 3) * 16 + ((l >> 5) & 1) * 8;
    *(uint4*)(ko + u * 8) = pack8(kt[a][c0], kt[a][c0 + 1], kt[a][c0 + 2], kt[a][c0 + 3],
                                  kt[a][c0 + 4], kt[a][c0 + 5], kt[a][c0 + 6], kt[a][c0 + 7]);
    *(uint4*)(vo + u * 8) = pack8(vt[c0][a], vt[c0 + 1][a], vt[c0 + 2][a], vt[c0 + 3][a],
                                  vt[c0 + 4][a], vt[c0 + 5][a], vt[c0 + 6][a], vt[c0 + 7][a]);
  }
}

// ---------------- Flash attention: 64q-waves (r11 champion + Z-hoist + early V reads) ----------------
__launch_bounds__(256, 2)
__global__ void attn_kernel(const float* __restrict__ q,
                            const ushort* __restrict__ Kb,
                            const ushort* __restrict__ Vtb,
                            ushort* __restrict__ X) {
  // SM[dbuf][K=0,V=1][4096 ushort]; epilogue reuses all 32 KB as f32 Ox.
  __shared__ __attribute__((aligned(16))) ushort SM[2][2][4096];
  __shared__ float Lb[2][2][32];
  __shared__ float Lb2[2][2][32];

  const int bid = blockIdx.x;
  const int swz = (bid & 7) * 64 + (bid >> 3);   // 512 blocks, bijective, XCD-contiguous
  const int bh = swz >> 5;
  const int qt = swz & 31;
  const int b = bh >> 2, h = bh & 3;
  const int tid = threadIdx.x;
  const int wid = tid >> 6;
  const int wq = wid & 1;        // q-block of 64 rows
  const int kh = wid >> 1;       // kv-half of the staged 64-kv tile
  const int lane = tid & 63;
  const int ln = lane & 31;
  const int hi = lane >> 5;

  const char* Kg = (const char*)Kb + (size_t)bh * NT * 8192;
  const char* Vg = (const char*)Vtb + (size_t)bh * NT * 8192;

  // ---- Q B-fragments for both q-groups, scale*log2e folded ----
  const float SC = 0.125f * 1.44269504f;
  const int qrow0 = qt * QBLK + wq * 64;
  short8 qf[2][4];
#pragma unroll
  for (int qg = 0; qg < 2; ++qg) {
    const float* Qg = q + ((size_t)b * N_ + qrow0 + qg * 32 + ln) * E_ + h * D_;
#pragma unroll
    for (int ks = 0; ks < 4; ++ks) {
      const float* p = Qg + ks * 16 + hi * 8;
      float4 x0 = *(const float4*)(p);
      float4 x1 = *(const float4*)(p + 4);
      short8 f;
      f[0] = (short)f2bf(x0.x * SC); f[1] = (short)f2bf(x0.y * SC);
      f[2] = (short)f2bf(x0.z * SC); f[3] = (short)f2bf(x0.w * SC);
      f[4] = (short)f2bf(x1.x * SC); f[5] = (short)f2bf(x1.y * SC);
      f[6] = (short)f2bf(x1.z * SC); f[7] = (short)f2bf(x1.w * SC);
      qf[qg][ks] = f;
    }
  }

  f32x16 O00 = (f32x16)0.0f, O01 = (f32x16)0.0f;   // [qg0][db0/1]
  f32x16 O10 = (f32x16)0.0f, O11 = (f32x16)0.0f;   // [qg1][db0/1]
  float lsum0 = 0.f, lsum1 = 0.f;

  // Loop-invariant zero accumulator: used as the C operand of the first MFMA of each
  // S-chain, so no per-round 32x v_mov zero-init of S0/S1 is needed (MFMA C != D).
  const f32x16 FZERO = (f32x16)0.0f;

  // ---- prologue: stage tile 0 (16 KB via 256 threads x 4 chunks) ----
  {
    uint4 a0 = *(const uint4*)(Kg + tid * 16);
    uint4 a1 = *(const uint4*)(Kg + 4096 + tid * 16);
    uint4 a2 = *(const uint4*)(Vg + tid * 16);
    uint4 a3 = *(const uint4*)(Vg + 4096 + tid * 16);
    *(uint4*)((char*)&SM[0][0][0] + tid * 16) = a0;
    *(uint4*)((char*)&SM[0][0][0] + 4096 + tid * 16) = a1;
    *(uint4*)((char*)&SM[0][1][0] + tid * 16) = a2;
    *(uint4*)((char*)&SM[0][1][0] + 4096 + tid * 16) = a3;
  }
  __syncthreads();
  int cur = 0;

  for (int t = 0; t < NT; ++t) {
    const bool pfn = (t + 1 < NT);
    uint4 rk0, rk1, rv0, rv1;
    if (pfn) {
      const char* kg = Kg + (size_t)(t + 1) * 8192;
      const char* vg = Vg + (size_t)(t + 1) * 8192;
      rk0 = *(const uint4*)(kg + tid * 16);
      rk1 = *(const uint4*)(kg + 4096 + tid * 16);
      rv0 = *(const uint4*)(vg + tid * 16);
      rv1 = *(const uint4*)(vg + 4096 + tid * 16);
    }

    const char* Kl = (const char*)&SM[cur][0][0];
    const char* Vl = (const char*)&SM[cur][1][0];

    // ---- K A-fragments for this wave's kv-half: 4 reads feed 8 MFMAs ----
    short8 kf[4];
#pragma unroll
    for (int ks = 0; ks < 4; ++ks)
      kf[ks] = *(short8*)(Kl + (kh * 4 + ks) * 1024 + lane * 16);

    // ---- V B-fragments issued EARLY (independent of S): LDS pipe fills them
    //      under the QK^T MFMA chain ----
    short8 vf[2][2];
#pragma unroll
    for (int db = 0; db < 2; ++db)
#pragma unroll
      for (int s = 0; s < 2; ++s)
        vf[db][s] = *(short8*)(Vl + (db * 4 + kh * 2 + s) * 1024 + lane * 16);

    // ---- S^T = K Q^T for both q-groups (first MFMA consumes FZERO as C) ----
    __builtin_amdgcn_s_setprio(1);
    f32x16 S0 = __builtin_amdgcn_mfma_f32_32x32x16_bf16(kf[0], qf[0][0], FZERO, 0, 0, 0);
    f32x16 S1 = __builtin_amdgcn_mfma_f32_32x32x16_bf16(kf[0], qf[1][0], FZERO, 0, 0, 0);
#pragma unroll
    for (int ks = 1; ks < 4; ++ks) {
      S0 = __builtin_amdgcn_mfma_f32_32x32x16_bf16(kf[ks], qf[0][ks], S0, 0, 0, 0);
      S1 = __builtin_amdgcn_mfma_f32_32x32x16_bf16(kf[ks], qf[1][ks], S1, 0, 0, 0);
    }
    __builtin_amdgcn_s_setprio(0);

    // ---- P = 2^S; tree sums ----
    float p0[16], p1[16];
#pragma unroll
    for (int i = 0; i < 16; ++i) {
      p0[i] = __builtin_amdgcn_exp2f(S0[i]);
      p1[i] = __builtin_amdgcn_exp2f(S1[i]);
    }
    {
      float s1[8];
#pragma unroll
      for (int i = 0; i < 8; ++i) s1[i] = p0[2 * i] + p0[2 * i + 1];
#pragma unroll
      for (int i = 0; i < 4; ++i) s1[i] = s1[2 * i] + s1[2 * i + 1];
      lsum0 += (s1[0] + s1[1]) + (s1[2] + s1[3]);
#pragma unroll
      for (int i = 0; i < 8; ++i) s1[i] = p1[2 * i] + p1[2 * i + 1];
#pragma unroll
      for (int i = 0; i < 4; ++i) s1[i] = s1[2 * i] + s1[2 * i + 1];
      lsum1 += (s1[0] + s1[1]) + (s1[2] + s1[3]);
    }

    // ---- pack P -> PV A-frags (cvt_pk + permlane32_swap) ----
    short8 pa0[2], pa1[2];
#pragma unroll
    for (int s = 0; s < 2; ++s) {
      int base = s * 8;
      {
        unsigned w0 = cvt_pk_bf16(p0[base + 0], p0[base + 1]);
        unsigned w2 = cvt_pk_bf16(p0[base + 4], p0[base + 5]);
        permlane32_swap(w0, w2);
        unsigned w1 = cvt_pk_bf16(p0[base + 2], p0[base + 3]);
        unsigned w3 = cvt_pk_bf16(p0[base + 6], p0[base + 7]);
        permlane32_swap(w1, w3);
        uint4 u; u.x = w0; u.y = w1; u.z = w2; u.w = w3;
        union { uint4 u4; short8 s8; } cv; cv.u4 = u;
        pa0[s] = cv.s8;
      }
      {
        unsigned w0 = cvt_pk_bf16(p1[base + 0], p1[base + 1]);
        unsigned w2 = cvt_pk_bf16(p1[base + 4], p1[base + 5]);
        permlane32_swap(w0, w2);
        unsigned w1 = cvt_pk_bf16(p1[base + 2], p1[base + 3]);
        unsigned w3 = cvt_pk_bf16(p1[base + 6], p1[base + 7]);
        permlane32_swap(w1, w3);
        uint4 u; u.x = w0; u.y = w1; u.z = w2; u.w = w3;
        union { uint4 u4; short8 s8; } cv; cv.u4 = u;
        pa1[s] = cv.s8;
      }
    }

    // ---- write staged regs into the other dbuf ----
    if (pfn) {
      *(uint4*)((char*)&SM[cur ^ 1][0][0] + tid * 16) = rk0;
      *(uint4*)((char*)&SM[cur ^ 1][0][0] + 4096 + tid * 16) = rk1;
      *(uint4*)((char*)&SM[cur ^ 1][1][0] + tid * 16) = rv0;
      *(uint4*)((char*)&SM[cur ^ 1][1][0] + 4096 + tid * 16) = rv1;
    }

    // ---- O += P V (both q-groups share vf) ----
    __builtin_amdgcn_s_setprio(1);
#pragma unroll
    for (int s = 0; s < 2; ++s) {
      O00 = __builtin_amdgcn_mfma_f32_32x32x16_bf16(pa0[s], vf[0][s], O00, 0, 0, 0);
      O01 = __builtin_amdgcn_mfma_f32_32x32x16_bf16(pa0[s], vf[1][s], O01, 0, 0, 0);
      O10 = __builtin_amdgcn_mfma_f32_32x32x16_bf16(pa1[s], vf[0][s], O10, 0, 0, 0);
      O11 = __builtin_amdgcn_mfma_f32_32x32x16_bf16(pa1[s], vf[1][s], O11, 0, 0, 0);
    }
    __builtin_amdgcn_s_setprio(0);

    __syncthreads();
    cur ^= 1;
  }

  // ---- epilogue: merge kv-halves via LDS (no rescale), normalize, write X ----
  float l0 = lsum0 + __shfl_xor(lsum0, 32);
  float l1 = lsum1 + __shfl_xor(lsum1, 32);
  float* Ox = (float*)&SM[0][0][0];   // all 32 KB
  if (kh) {
    if (lane < 32) { Lb[wq][0][ln] = l0; Lb[wq][1][ln] = l1; }
#pragma unroll
    for (int r2 = 0; r2 < 16; ++r2) {
      Ox[wq * 4096 + 0 * 2048 + 0 * 1024 + r2 * 64 + lane] = O00[r2];
      Ox[wq * 4096 + 0 * 2048 + 1 * 1024 + r2 * 64 + lane] = O01[r2];
      Ox[wq * 4096 + 1 * 2048 + 0 * 1024 + r2 * 64 + lane] = O10[r2];
      Ox[wq * 4096 + 1 * 2048 + 1 * 1024 + r2 * 64 + lane] = O11[r2];
    }
  }
  __syncthreads();
  if (!kh) {
    float lt0 = l0 + Lb[wq][0][ln];
    float lt1 = l1 + Lb[wq][1][ln];
    if (lane < 32) { Lb2[wq][0][ln] = lt0; Lb2[wq][1][ln] = lt1; }
    asm volatile("" ::: "memory");
#pragma unroll
    for (int r2 = 0; r2 < 16; ++r2) {
      O00[r2] += Ox[wq * 4096 + 0 * 2048 + 0 * 1024 + r2 * 64 + lane];
      O01[r2] += Ox[wq * 4096 + 0 * 2048 + 1 * 1024 + r2 * 64 + lane];
      O10[r2] += Ox[wq * 4096 + 1 * 2048 + 0 * 1024 + r2 * 64 + lane];
      O11[r2] += Ox[wq * 4096 + 1 * 2048 + 1 * 1024 + r2 * 64 + lane];
    }
    ushort* Xp = X + ((size_t)b * N_) * E_ + h * D_;
#pragma unroll
    for (int r2 = 0; r2 < 16; ++r2) {
      int crow = (r2 & 3) + 8 * (r2 >> 2) + 4 * hi;
      float i0 = 1.0f / Lb2[wq][0][crow];
      float i1 = 1.0f / Lb2[wq][1][crow];
      int q0 = qrow0 + crow;
      int q1 = qrow0 + 32 + crow;
      Xp[(size_t)q0 * E_ + ln]      = f2bf(O00[r2] * i0);
      Xp[(size_t)q0 * E_ + 32 + ln] = f2bf(O01[r2] * i0);
      Xp[(size_t)q1 * E_ + ln]      = f2bf(O10[r2] * i1);
      Xp[(size_t)q1 * E_ + 32 + ln] = f2bf(O11[r2] * i1);
    }
  }
}

// ---------------- Output projection: out = X @ W^T + b ----------------
__launch_bounds__(256, 2)
__global__ void proj_kernel(const ushort* __restrict__ X, const ushort* __restrict__ Wb,
                            const float* __restrict__ bias, float* __restrict__ out) {
  const int m0   = blockIdx.x * 64;
  const int tid  = threadIdx.x;
  const int wid  = tid >> 6;
  const int lane = tid & 63;
  const int g    = lane >> 4;
  const int lr   = lane & 15;
  const int n0   = wid * 64;

  f32x4 acc[4][4];
  for (int mb = 0; mb < 4; ++mb)
    for (int nb = 0; nb < 4; ++nb)
      acc[mb][nb] = (f32x4){0.f, 0.f, 0.f, 0.f};

  for (int k0 = 0; k0 < E_; k0 += 32) {
    short8 af[4], bfr[4];
    for (int mb = 0; mb < 4; ++mb)
      af[mb] = *(const short8*)(X + (size_t)(m0 + mb * 16 + lr) * E_ + k0 + g * 8);
    for (int nb = 0; nb < 4; ++nb)
      bfr[nb] = *(const short8*)(Wb + (size_t)(n0 + nb * 16 + lr) * E_ + k0 + g * 8);
    for (int mb = 0; mb < 4; ++mb)
      for (int nb = 0; nb < 4; ++nb)
        acc[mb][nb] = __builtin_amdgcn_mfma_f32_16x16x32_bf16(af[mb], bfr[nb], acc[mb][nb], 0, 0, 0);
  }

  for (int nb = 0; nb < 4; ++nb) {
    float bv = bias[n0 + nb * 16 + lr];
    for (int mb = 0; mb < 4; ++mb)
      for (int r = 0; r < 4; ++r)
        out[(size_t)(m0 + mb * 16 + g * 4 + r) * E_ + n0 + nb * 16 + lr] = acc[mb][nb][r] + bv;
  }
}

extern "C" void kernel_launch(void* const* d_in, const int* in_sizes, int n_in,
                              void* d_out, int out_size, void* d_ws, size_t ws_size,
                              hipStream_t stream) {
  const float* q    = (const float*)d_in[0];
  const float* k    = (const float*)d_in[1];
  const float* v    = (const float*)d_in[2];
  const float* W    = (const float*)d_in[3];
  const float* bias = (const float*)d_in[4];

  char* ws = (char*)d_ws;
  ushort* X   = (ushort*)ws;                                  // 8 MiB
  ushort* Wb  = (ushort*)(ws + 8388608);                      // 128 KiB
  ushort* Kb  = (ushort*)(ws + 8388608 + 131072);             // 8 MiB
  ushort* Vtb = (ushort*)(ws + 8388608 + 131072 + 8388608);   // 8 MiB

  cast_w_kernel<<<64, 256, 0, stream>>>(W, Wb);
  prep_kv<<<B_ * H_ * NT, 256, 0, stream>>>(k, v, Kb, Vtb);
  attn_kernel<<<B_ * H_ * (N_ / QBLK), 256, 0, stream>>>(q, Kb, Vtb, X);
  proj_kernel<<<(B_ * N_) / 64, 256, 0, stream>>>(X, Wb, bias, (float*)d_out);
}

// Round 19
// 107.164 us; speedup vs baseline: 1.0832x; 1.0244x over previous
//
#include <hip/hip_runtime.h>
#include <hip/hip_bf16.h>

#define B_ 4
#define H_ 4
#define N_ 4096
#define D_ 64
#define E_ 256
#define KVB 64
#define QBLK 128            // 4 waves: 2 q-groups(64q) x 2 kv-halves
#define NT (N_ / KVB)

typedef short short8 __attribute__((ext_vector_type(8)));
typedef float f32x4 __attribute__((ext_vector_type(4)));
typedef float f32x16 __attribute__((ext_vector_type(16)));

__device__ __forceinline__ ushort f2bf(float f) {
  union { float f; unsigned u; } a; a.f = f;
  unsigned r = a.u + 0x7fffu + ((a.u >> 16) & 1u);
  return (ushort)(r >> 16);
}

__device__ __forceinline__ uint4 pack8(float a0, float a1, float a2, float a3,
                                       float a4, float a5, float a6, float a7) {
  uint4 u;
  u.x = (unsigned)f2bf(a0) | ((unsigned)f2bf(a1) << 16);
  u.y = (unsigned)f2bf(a2) | ((unsigned)f2bf(a3) << 16);
  u.z = (unsigned)f2bf(a4) | ((unsigned)f2bf(a5) << 16);
  u.w = (unsigned)f2bf(a6) | ((unsigned)f2bf(a7) << 16);
  return u;
}

__device__ __forceinline__ unsigned cvt_pk_bf16(float lo, float hi) {
  unsigned r;
  asm("v_cvt_pk_bf16_f32 %0, %1, %2" : "=v"(r) : "v"(lo), "v"(hi));
  return r;
}

__device__ __forceinline__ void permlane32_swap(unsigned &a, unsigned &b) {
  asm volatile("v_permlane32_swap_b32 %0, %1" : "+v"(a), "+v"(b));
}

// ---------------- Pre-pass: K/V -> MFMA-fragment-order bf16 tiles; 64 tail blocks cast W ----------------
__global__ void prep_kv(const float* __restrict__ k, const float* __restrict__ v,
                        const float* __restrict__ W,
                        ushort* __restrict__ Kb, ushort* __restrict__ Vtb,
                        ushort* __restrict__ Wb) {
  const int gid = blockIdx.x;
  if (gid >= B_ * H_ * NT) {
    // W cast tail: W = 256x256 f32 = 16384 float4; 64 blocks x 256 threads x 1 float4.
    int i = (gid - B_ * H_ * NT) * 256 + threadIdx.x;
    float4 x = ((const float4*)W)[i];
    ushort4 o;
    o.x = f2bf(x.x); o.y = f2bf(x.y); o.z = f2bf(x.z); o.w = f2bf(x.w);
    ((ushort4*)Wb)[i] = o;
    return;
  }
  __shared__ float kt[64][65];
  __shared__ float vt[64][65];
  const int bh = gid >> 6, t = gid & 63;
  const int b = bh >> 2, h = bh & 3;
  const int tid = threadIdx.x;
  const int rr = tid >> 4, cc = (tid & 15) * 4;
  const float* kg = k + ((size_t)b * N_ + t * 64) * E_ + h * 64;
  const float* vg = v + ((size_t)b * N_ + t * 64) * E_ + h * 64;
  ushort* ko = Kb + (size_t)gid * 4096;
  ushort* vo = Vtb + (size_t)gid * 4096;

  for (int it = 0; it < 4; ++it) {
    int r = rr + it * 16;
    float4 kx = *(const float4*)(kg + (size_t)r * E_ + cc);
    float4 vx = *(const float4*)(vg + (size_t)r * E_ + cc);
    kt[r][cc] = kx.x; kt[r][cc + 1] = kx.y; kt[r][cc + 2] = kx.z; kt[r][cc + 3] = kx.w;
    vt[r][cc] = vx.x; vt[r][cc + 1] = vx.y; vt[r][cc + 2] = vx.z; vt[r][cc + 3] = vx.w;
  }
  __syncthreads();

  for (int j = 0; j < 2; ++j) {
    int u = j * 256 + tid;
    int frag = u >> 6, l = u & 63;
    int a = (frag >> 2) * 32 + (l & 31);
    int c0 = (frag & 3) * 16 + ((l >> 5) & 1) * 8;
    *(uint4*)(ko + u * 8) = pack8(kt[a][c0], kt[a][c0 + 1], kt[a][c0 + 2], kt[a][c0 + 3],
                                  kt[a][c0 + 4], kt[a][c0 + 5], kt[a][c0 + 6], kt[a][c0 + 7]);
    *(uint4*)(vo + u * 8) = pack8(vt[c0][a], vt[c0 + 1][a], vt[c0 + 2][a], vt[c0 + 3][a],
                                  vt[c0 + 4][a], vt[c0 + 5][a], vt[c0 + 6][a], vt[c0 + 7][a]);
  }
}

// ---------------- Flash attention: 64q-waves, frag-linear LDS, in-register softmax ----------------
__launch_bounds__(256, 2)
__global__ void attn_kernel(const float* __restrict__ q,
                            const ushort* __restrict__ Kb,
                            const ushort* __restrict__ Vtb,
                            ushort* __restrict__ X) {
  __shared__ __attribute__((aligned(16))) ushort SM[2][2][4096];
  __shared__ float Lb[2][2][32];
  __shared__ float Lb2[2][2][32];

  const int bid = blockIdx.x;
  const int swz = (bid & 7) * 64 + (bid >> 3);   // 512 blocks, bijective, XCD-contiguous
  const int bh = swz >> 5;
  const int qt = swz & 31;
  const int b = bh >> 2, h = bh & 3;
  const int tid = threadIdx.x;
  const int wid = tid >> 6;
  const int wq = wid & 1;        // q-block of 64 rows
  const int kh = wid >> 1;       // kv-half of the staged 64-kv tile
  const int lane = tid & 63;
  const int ln = lane & 31;
  const int hi = lane >> 5;

  const char* Kg = (const char*)Kb + (size_t)bh * NT * 8192;
  const char* Vg = (const char*)Vtb + (size_t)bh * NT * 8192;

  const float SC = 0.125f * 1.44269504f;
  const int qrow0 = qt * QBLK + wq * 64;
  short8 qf[2][4];
#pragma unroll
  for (int qg = 0; qg < 2; ++qg) {
    const float* Qg = q + ((size_t)b * N_ + qrow0 + qg * 32 + ln) * E_ + h * D_;
#pragma unroll
    for (int ks = 0; ks < 4; ++ks) {
      const float* p = Qg + ks * 16 + hi * 8;
      float4 x0 = *(const float4*)(p);
      float4 x1 = *(const float4*)(p + 4);
      short8 f;
      f[0] = (short)f2bf(x0.x * SC); f[1] = (short)f2bf(x0.y * SC);
      f[2] = (short)f2bf(x0.z * SC); f[3] = (short)f2bf(x0.w * SC);
      f[4] = (short)f2bf(x1.x * SC); f[5] = (short)f2bf(x1.y * SC);
      f[6] = (short)f2bf(x1.z * SC); f[7] = (short)f2bf(x1.w * SC);
      qf[qg][ks] = f;
    }
  }

  f32x16 O00 = (f32x16)0.0f, O01 = (f32x16)0.0f;
  f32x16 O10 = (f32x16)0.0f, O11 = (f32x16)0.0f;
  float lsum0 = 0.f, lsum1 = 0.f;
  const f32x16 FZERO = (f32x16)0.0f;

  {
    uint4 a0 = *(const uint4*)(Kg + tid * 16);
    uint4 a1 = *(const uint4*)(Kg + 4096 + tid * 16);
    uint4 a2 = *(const uint4*)(Vg + tid * 16);
    uint4 a3 = *(const uint4*)(Vg + 4096 + tid * 16);
    *(uint4*)((char*)&SM[0][0][0] + tid * 16) = a0;
    *(uint4*)((char*)&SM[0][0][0] + 4096 + tid * 16) = a1;
    *(uint4*)((char*)&SM[0][1][0] + tid * 16) = a2;
    *(uint4*)((char*)&SM[0][1][0] + 4096 + tid * 16) = a3;
  }
  __syncthreads();
  int cur = 0;

  for (int t = 0; t < NT; ++t) {
    const bool pfn = (t + 1 < NT);
    uint4 rk0, rk1, rv0, rv1;
    if (pfn) {
      const char* kg = Kg + (size_t)(t + 1) * 8192;
      const char* vg = Vg + (size_t)(t + 1) * 8192;
      rk0 = *(const uint4*)(kg + tid * 16);
      rk1 = *(const uint4*)(kg + 4096 + tid * 16);
      rv0 = *(const uint4*)(vg + tid * 16);
      rv1 = *(const uint4*)(vg + 4096 + tid * 16);
    }

    const char* Kl = (const char*)&SM[cur][0][0];
    const char* Vl = (const char*)&SM[cur][1][0];

    short8 kf[4];
#pragma unroll
    for (int ks = 0; ks < 4; ++ks)
      kf[ks] = *(short8*)(Kl + (kh * 4 + ks) * 1024 + lane * 16);

    short8 vf[2][2];
#pragma unroll
    for (int db = 0; db < 2; ++db)
#pragma unroll
      for (int s = 0; s < 2; ++s)
        vf[db][s] = *(short8*)(Vl + (db * 4 + kh * 2 + s) * 1024 + lane * 16);

    __builtin_amdgcn_s_setprio(1);
    f32x16 S0 = __builtin_amdgcn_mfma_f32_32x32x16_bf16(kf[0], qf[0][0], FZERO, 0, 0, 0);
    f32x16 S1 = __builtin_amdgcn_mfma_f32_32x32x16_bf16(kf[0], qf[1][0], FZERO, 0, 0, 0);
#pragma unroll
    for (int ks = 1; ks < 4; ++ks) {
      S0 = __builtin_amdgcn_mfma_f32_32x32x16_bf16(kf[ks], qf[0][ks], S0, 0, 0, 0);
      S1 = __builtin_amdgcn_mfma_f32_32x32x16_bf16(kf[ks], qf[1][ks], S1, 0, 0, 0);
    }
    __builtin_amdgcn_s_setprio(0);

    float p0[16], p1[16];
#pragma unroll
    for (int i = 0; i < 16; ++i) {
      p0[i] = __builtin_amdgcn_exp2f(S0[i]);
      p1[i] = __builtin_amdgcn_exp2f(S1[i]);
    }
    {
      float s1[8];
#pragma unroll
      for (int i = 0; i < 8; ++i) s1[i] = p0[2 * i] + p0[2 * i + 1];
#pragma unroll
      for (int i = 0; i < 4; ++i) s1[i] = s1[2 * i] + s1[2 * i + 1];
      lsum0 += (s1[0] + s1[1]) + (s1[2] + s1[3]);
#pragma unroll
      for (int i = 0; i < 8; ++i) s1[i] = p1[2 * i] + p1[2 * i + 1];
#pragma unroll
      for (int i = 0; i < 4; ++i) s1[i] = s1[2 * i] + s1[2 * i + 1];
      lsum1 += (s1[0] + s1[1]) + (s1[2] + s1[3]);
    }

    short8 pa0[2], pa1[2];
#pragma unroll
    for (int s = 0; s < 2; ++s) {
      int base = s * 8;
      {
        unsigned w0 = cvt_pk_bf16(p0[base + 0], p0[base + 1]);
        unsigned w2 = cvt_pk_bf16(p0[base + 4], p0[base + 5]);
        permlane32_swap(w0, w2);
        unsigned w1 = cvt_pk_bf16(p0[base + 2], p0[base + 3]);
        unsigned w3 = cvt_pk_bf16(p0[base + 6], p0[base + 7]);
        permlane32_swap(w1, w3);
        uint4 u; u.x = w0; u.y = w1; u.z = w2; u.w = w3;
        union { uint4 u4; short8 s8; } cv; cv.u4 = u;
        pa0[s] = cv.s8;
      }
      {
        unsigned w0 = cvt_pk_bf16(p1[base + 0], p1[base + 1]);
        unsigned w2 = cvt_pk_bf16(p1[base + 4], p1[base + 5]);
        permlane32_swap(w0, w2);
        unsigned w1 = cvt_pk_bf16(p1[base + 2], p1[base + 3]);
        unsigned w3 = cvt_pk_bf16(p1[base + 6], p1[base + 7]);
        permlane32_swap(w1, w3);
        uint4 u; u.x = w0; u.y = w1; u.z = w2; u.w = w3;
        union { uint4 u4; short8 s8; } cv; cv.u4 = u;
        pa1[s] = cv.s8;
      }
    }

    if (pfn) {
      *(uint4*)((char*)&SM[cur ^ 1][0][0] + tid * 16) = rk0;
      *(uint4*)((char*)&SM[cur ^ 1][0][0] + 4096 + tid * 16) = rk1;
      *(uint4*)((char*)&SM[cur ^ 1][1][0] + tid * 16) = rv0;
      *(uint4*)((char*)&SM[cur ^ 1][1][0] + 4096 + tid * 16) = rv1;
    }

    __builtin_amdgcn_s_setprio(1);
#pragma unroll
    for (int s = 0; s < 2; ++s) {
      O00 = __builtin_amdgcn_mfma_f32_32x32x16_bf16(pa0[s], vf[0][s], O00, 0, 0, 0);
      O01 = __builtin_amdgcn_mfma_f32_32x32x16_bf16(pa0[s], vf[1][s], O01, 0, 0, 0);
      O10 = __builtin_amdgcn_mfma_f32_32x32x16_bf16(pa1[s], vf[0][s], O10, 0, 0, 0);
      O11 = __builtin_amdgcn_mfma_f32_32x32x16_bf16(pa1[s], vf[1][s], O11, 0, 0, 0);
    }
    __builtin_amdgcn_s_setprio(0);

    __syncthreads();
    cur ^= 1;
  }

  // ---- epilogue ----
  float l0 = lsum0 + __shfl_xor(lsum0, 32);
  float l1 = lsum1 + __shfl_xor(lsum1, 32);
  float* Ox = (float*)&SM[0][0][0];
  if (kh) {
    if (lane < 32) { Lb[wq][0][ln] = l0; Lb[wq][1][ln] = l1; }
#pragma unroll
    for (int r2 = 0; r2 < 16; ++r2) {
      Ox[wq * 4096 + 0 * 2048 + 0 * 1024 + r2 * 64 + lane] = O00[r2];
      Ox[wq * 4096 + 0 * 2048 + 1 * 1024 + r2 * 64 + lane] = O01[r2];
      Ox[wq * 4096 + 1 * 2048 + 0 * 1024 + r2 * 64 + lane] = O10[r2];
      Ox[wq * 4096 + 1 * 2048 + 1 * 1024 + r2 * 64 + lane] = O11[r2];
    }
  }
  __syncthreads();
  if (!kh) {
    float lt0 = l0 + Lb[wq][0][ln];
    float lt1 = l1 + Lb[wq][1][ln];
    if (lane < 32) { Lb2[wq][0][ln] = lt0; Lb2[wq][1][ln] = lt1; }
    asm volatile("" ::: "memory");
#pragma unroll
    for (int r2 = 0; r2 < 16; ++r2) {
      O00[r2] += Ox[wq * 4096 + 0 * 2048 + 0 * 1024 + r2 * 64 + lane];
      O01[r2] += Ox[wq * 4096 + 0 * 2048 + 1 * 1024 + r2 * 64 + lane];
      O10[r2] += Ox[wq * 4096 + 1 * 2048 + 0 * 1024 + r2 * 64 + lane];
      O11[r2] += Ox[wq * 4096 + 1 * 2048 + 1 * 1024 + r2 * 64 + lane];
    }
    ushort* Xp = X + ((size_t)b * N_) * E_ + h * D_;
#pragma unroll
    for (int r2 = 0; r2 < 16; ++r2) {
      int crow = (r2 & 3) + 8 * (r2 >> 2) + 4 * hi;
      float i0 = 1.0f / Lb2[wq][0][crow];
      float i1 = 1.0f / Lb2[wq][1][crow];
      int q0 = qrow0 + crow;
      int q1 = qrow0 + 32 + crow;
      Xp[(size_t)q0 * E_ + ln]      = f2bf(O00[r2] * i0);
      Xp[(size_t)q0 * E_ + 32 + ln] = f2bf(O01[r2] * i0);
      Xp[(size_t)q1 * E_ + ln]      = f2bf(O10[r2] * i1);
      Xp[(size_t)q1 * E_ + 32 + ln] = f2bf(O11[r2] * i1);
    }
  }
}

// ---------------- Output projection: out = X @ W^T + b (512 blocks x 32 rows) ----------------
__launch_bounds__(256, 2)
__global__ void proj_kernel(const ushort* __restrict__ X, const ushort* __restrict__ Wb,
                            const float* __restrict__ bias, float* __restrict__ out) {
  const int m0   = blockIdx.x * 32;
  const int tid  = threadIdx.x;
  const int wid  = tid >> 6;
  const int lane = tid & 63;
  const int g    = lane >> 4;
  const int lr   = lane & 15;
  const int n0   = wid * 64;

  f32x4 acc[2][4];
  for (int mb = 0; mb < 2; ++mb)
    for (int nb = 0; nb < 4; ++nb)
      acc[mb][nb] = (f32x4){0.f, 0.f, 0.f, 0.f};

  for (int k0 = 0; k0 < E_; k0 += 32) {
    short8 af[2], bfr[4];
    for (int mb = 0; mb < 2; ++mb)
      af[mb] = *(const short8*)(X + (size_t)(m0 + mb * 16 + lr) * E_ + k0 + g * 8);
    for (int nb = 0; nb < 4; ++nb)
      bfr[nb] = *(const short8*)(Wb + (size_t)(n0 + nb * 16 + lr) * E_ + k0 + g * 8);
    for (int mb = 0; mb < 2; ++mb)
      for (int nb = 0; nb < 4; ++nb)
        acc[mb][nb] = __builtin_amdgcn_mfma_f32_16x16x32_bf16(af[mb], bfr[nb], acc[mb][nb], 0, 0, 0);
  }

  for (int nb = 0; nb < 4; ++nb) {
    float bv = bias[n0 + nb * 16 + lr];
    for (int mb = 0; mb < 2; ++mb)
      for (int r = 0; r < 4; ++r)
        out[(size_t)(m0 + mb * 16 + g * 4 + r) * E_ + n0 + nb * 16 + lr] = acc[mb][nb][r] + bv;
  }
}

extern "C" void kernel_launch(void* const* d_in, const int* in_sizes, int n_in,
                              void* d_out, int out_size, void* d_ws, size_t ws_size,
                              hipStream_t stream) {
  const float* q    = (const float*)d_in[0];
  const float* k    = (const float*)d_in[1];
  const float* v    = (const float*)d_in[2];
  const float* W    = (const float*)d_in[3];
  const float* bias = (const float*)d_in[4];

  char* ws = (char*)d_ws;
  ushort* X   = (ushort*)ws;                                  // 8 MiB
  ushort* Wb  = (ushort*)(ws + 8388608);                      // 128 KiB
  ushort* Kb  = (ushort*)(ws + 8388608 + 131072);             // 8 MiB
  ushort* Vtb = (ushort*)(ws + 8388608 + 131072 + 8388608);   // 8 MiB

  // prep_kv: 1024 KV-tile blocks + 64 tail blocks casting W (16384 float4 total)
  prep_kv<<<B_ * H_ * NT + 64, 256, 0, stream>>>(k, v, W, Kb, Vtb, Wb);
  attn_kernel<<<B_ * H_ * (N_ / QBLK), 256, 0, stream>>>(q, Kb, Vtb, X);
  proj_kernel<<<(B_ * N_) / 32, 256, 0, stream>>>(X, Wb, bias, (float*)d_out);
}